// Round 13
// baseline (75.923 us; speedup 1.0000x reference)
//
#include <hip/hip_runtime.h>
#include <hip/hip_bf16.h>
#include <math.h>
#include <stdint.h>

namespace {

constexpr int Bc = 16, Nc = 1024, Ec = 128, Hc = 8, KDc = 16, HKc = 128;
// 1/sqrt(KD) * log2(e): fold softmax scale + base-2 conversion into Q
constexpr float SCALE = 0.25f * 1.4426950408889634f;

typedef __attribute__((ext_vector_type(4))) short short4v;
typedef __attribute__((ext_vector_type(8))) short short8;
typedef __attribute__((ext_vector_type(4))) float f32x4;
typedef __attribute__((ext_vector_type(4))) int int4v;

__device__ inline uint16_t f2bf(float f) {
  __hip_bfloat16 h = __float2bfloat16(f);
  uint16_t s; __builtin_memcpy(&s, &h, 2);
  return s;
}

// RNE pair pack for output stores
__device__ inline uint32_t pk2(float a, float b) {
  return (uint32_t)f2bf(a) | ((uint32_t)f2bf(b) << 16);
}

// packed f32->bf16 (P-values / epilogue fragments)
__device__ inline uint32_t cvt_pk_bf16(float a, float b) {
  uint32_t r;
  asm("v_cvt_pk_bf16_f32 %0, %1, %2" : "=v"(r) : "v"(a), "v"(b));
  return r;
}

// masked exp2: p = exp2(s) if adjacency bit set else 0  (sbfe -> 0/-1 mask)
__device__ inline float mexp(float s, uint32_t w, int bit) {
  const uint32_t m = (uint32_t)__builtin_amdgcn_sbfe((int)w, bit, 1);
  return __uint_as_float(__float_as_uint(__builtin_amdgcn_exp2f(s)) & m);
}

// hi/lo split: x ~= hi + lo, both bf16 RNE
__device__ inline void split8(const float* x, short8& hi, short8& lo) {
  #pragma unroll
  for (int i = 0; i < 8; ++i) {
    const uint16_t h = f2bf(x[i]);
    hi[i] = (short)h;
    lo[i] = (short)f2bf(x[i] - __uint_as_float((uint32_t)h << 16));
  }
}
__device__ inline short8 round8(const float* x) {
  short8 r;
  #pragma unroll
  for (int i = 0; i < 8; ++i) r[i] = (short)f2bf(x[i]);
  return r;
}

// ---------------- Kernel 1: MFMA QKV projection (hi/lo) + bitpack + WoutF pack ----
// 1024 blocks x 512 threads (8 waves = 8 heads), 16 tokens/block -> 32 waves/CU grid
// ceiling, halved per-wave chains vs r12. Fragment layouts unchanged (validated):
// a 16-token block writes the parity-selected half (elems 0-3 or 4-7) of each K/V
// lane-fragment and one full Q qtile.
__global__ __launch_bounds__(512, 8) void qkv_kernel(
    const float* __restrict__ hin,
    const float* __restrict__ Wq, const float* __restrict__ Wk, const float* __restrict__ Wv,
    const float* __restrict__ Wout, const int* __restrict__ adj,
    uint16_t* __restrict__ Qf, uint16_t* __restrict__ Kf, uint16_t* __restrict__ Vf,
    uint32_t* __restrict__ bits, uint16_t* __restrict__ WoutF)
{
  const int t = threadIdx.x;
  const int hd = t >> 6;            // wave = head
  const int l = t & 63;
  const int g = l >> 4, c = l & 15;

  // ---- adjacency bit-pack: 8192 waves x 32 coalesced chunks, 8 loads in flight ----
  {
    const int gw = blockIdx.x * 8 + hd;
    const int* asrc = adj + (size_t)gw * 2048 + l;   // 32 chunks x 64 ints
    uint2* bdst = reinterpret_cast<uint2*>(bits) + (size_t)gw * 32;
    #pragma unroll 8
    for (int cc = 0; cc < 32; ++cc) {
      const unsigned long long m = __ballot(asrc[(size_t)cc * 64] != 0);
      if (l == 0) bdst[cc] = make_uint2((uint32_t)m, (uint32_t)(m >> 32));
    }
  }

  // ---- Wout fragment pack (block 0 only; 16384 elems, 32/thread) ----
  if (blockIdx.x == 0) {
    #pragma unroll 4
    for (int it = 0; it < 32; ++it) {
      const int idx = t + it * 512;
      const int elem = idx & 7, lane = (idx >> 3) & 63;
      const int kstep = (idx >> 9) & 3, etile = idx >> 11;
      const int hk = (elem & 3) + 4 * (lane >> 4) + 16 * (elem >> 2) + 32 * kstep;
      const int e = etile * 16 + (lane & 15);
      WoutF[idx] = f2bf(Wout[hk * 128 + e]);
    }
  }

  const int b_tok = blockIdx.x;     // 16-token tile index (global)
  const int b = b_tok >> 6;
  const int qtile = b_tok & 63;
  const int kblk = (b_tok >> 1) & 31;
  const int par = b_tok & 1;        // which half of the 32-key fragment block

  f32x4 Qa = {0,0,0,0}, Ka = {0,0,0,0}, Va = {0,0,0,0};

  #pragma unroll
  for (int s = 0; s < 4; ++s) {
    const int ebase = (s * 32 + 4 * g) * 16 + c;
    const float* wqp = Wq + hd * 2048 + ebase;
    const float* wkp = Wk + hd * 2048 + ebase;
    const float* wvp = Wv + hd * 2048 + ebase;
    float wx[8];
    short8 wqh, wql, wkh, wkl, wv8;
    wx[0]=wqp[0]; wx[1]=wqp[16]; wx[2]=wqp[32]; wx[3]=wqp[48];
    wx[4]=wqp[256]; wx[5]=wqp[272]; wx[6]=wqp[288]; wx[7]=wqp[304];
    split8(wx, wqh, wql);
    wx[0]=wkp[0]; wx[1]=wkp[16]; wx[2]=wkp[32]; wx[3]=wkp[48];
    wx[4]=wkp[256]; wx[5]=wkp[272]; wx[6]=wkp[288]; wx[7]=wkp[304];
    split8(wx, wkh, wkl);
    wx[0]=wvp[0]; wx[1]=wvp[16]; wx[2]=wvp[32]; wx[3]=wvp[48];
    wx[4]=wvp[256]; wx[5]=wvp[272]; wx[6]=wvp[288]; wx[7]=wvp[304];
    wv8 = round8(wx);

    const size_t grow = (size_t)b_tok * 16 + c;
    const float4 lo4 = *reinterpret_cast<const float4*>(hin + grow * 128 + s * 32 + 4 * g);
    const float4 hi4 = *reinterpret_cast<const float4*>(hin + grow * 128 + s * 32 + 16 + 4 * g);
    float hx[8];
    hx[0]=lo4.x; hx[1]=lo4.y; hx[2]=lo4.z; hx[3]=lo4.w;
    hx[4]=hi4.x; hx[5]=hi4.y; hx[6]=hi4.z; hx[7]=hi4.w;
    short8 hh, hl; split8(hx, hh, hl);

    Qa = __builtin_amdgcn_mfma_f32_16x16x32_bf16(wqh, hh, Qa, 0, 0, 0);
    Qa = __builtin_amdgcn_mfma_f32_16x16x32_bf16(wqh, hl, Qa, 0, 0, 0);
    Qa = __builtin_amdgcn_mfma_f32_16x16x32_bf16(wql, hh, Qa, 0, 0, 0);
    Ka = __builtin_amdgcn_mfma_f32_16x16x32_bf16(wkh, hh, Ka, 0, 0, 0);
    Ka = __builtin_amdgcn_mfma_f32_16x16x32_bf16(wkh, hl, Ka, 0, 0, 0);
    Ka = __builtin_amdgcn_mfma_f32_16x16x32_bf16(wkl, hh, Ka, 0, 0, 0);
    Va = __builtin_amdgcn_mfma_f32_16x16x32_bf16(hh, wv8, Va, 0, 0, 0);
    Va = __builtin_amdgcn_mfma_f32_16x16x32_bf16(hl, wv8, Va, 0, 0, 0);
  }

  // ---- stores: lane-local D regs, 8B each ----
  {
    uint2 q0;
    q0.x = pk2(Qa[0] * SCALE, Qa[1] * SCALE);
    q0.y = pk2(Qa[2] * SCALE, Qa[3] * SCALE);
    *reinterpret_cast<uint2*>(
        Qf + ((((size_t)b * Hc + hd) * 64 + qtile) * 64 + l) * 4) = q0;
  }
  {
    uint2 kw;
    kw.x = pk2(Ka[0], Ka[1]); kw.y = pk2(Ka[2], Ka[3]);
    *reinterpret_cast<uint2*>(
        Kf + ((((size_t)b * Hc + hd) * 32 + kblk) * 64 + l) * 8 + 4 * par) = kw;
    uint2 vw;
    vw.x = pk2(Va[0], Va[1]); vw.y = pk2(Va[2], Va[3]);
    *reinterpret_cast<uint2*>(
        Vf + ((((size_t)b * Hc + hd) * 32 + kblk) * 64 + l) * 8 + 4 * par) = vw;
  }
}

// ---------------- Kernel 2: 16x16-fragment MFMA masked attention + MFMA out-proj ----
// BYTE-IDENTICAL to round 12 (validated, ~15 us).
__global__ __launch_bounds__(512, 4) void attn_kernel(
    const uint16_t* __restrict__ Qf, const uint16_t* __restrict__ Kf,
    const uint16_t* __restrict__ Vf, const uint32_t* __restrict__ bits,
    const uint16_t* __restrict__ WoutF,
    const float* __restrict__ hin, float* __restrict__ out)
{
  __shared__ uint32_t adj_lds[16][33];   // [q-row][word], padded
  __shared__ float heads[16][132];       // [q-row][h*16+kd], padded
  __shared__ float S_lds[8][16];         // [head][q-row]

  const int t = threadIdx.x;
  // XCD-aware swizzle: 1024 blocks, 128/XCD
  const int bid = blockIdx.x;
  const int swz = (bid & 7) * 128 + (bid >> 3);
  const int b = swz >> 6;
  const int qblk = swz & 63;
  const int hd = t >> 6, l = t & 63;
  const int g = l >> 4, q = l & 15;

  // stage adjacency bit words: 16 rows x 32 words, fully coalesced
  adj_lds[t >> 5][t & 31] =
      bits[((size_t)b * Nc + qblk * 16 + (t >> 5)) * 32 + (t & 31)];

  // Q fragment: 4 bf16 (kd = 4g+i), upper 4 k-slots zero
  const short4v q4 = *reinterpret_cast<const short4v*>(
      Qf + ((((size_t)b * Hc + hd) * 64 + qblk) * 64 + l) * 4);
  short8 qf8;
  #pragma unroll
  for (int i = 0; i < 4; ++i) { qf8[i] = q4[i]; qf8[4 + i] = 0; }

  __syncthreads();

  f32x4 acc = {0.f, 0.f, 0.f, 0.f};
  const f32x4 zc = {0.f, 0.f, 0.f, 0.f};
  float S = 0.f;

  const uint16_t* kb = Kf + (((size_t)b * Hc + hd) * 32) * 512 + (size_t)l * 8;
  const uint16_t* vb = Vf + (((size_t)b * Hc + hd) * 32) * 512 + (size_t)l * 8;

  // prologue: loads for kblk = 0
  int4v kfw = *reinterpret_cast<const int4v*>(kb);
  int4v vfw = *reinterpret_cast<const int4v*>(vb);

  #pragma unroll 2
  for (int kblk = 0; kblk < 32; ++kblk) {
    const int4v kc = kfw, vc = vfw;
    // prefetch next iteration (one-past-end lands in adjacent mapped workspace)
    kfw = *reinterpret_cast<const int4v*>(kb + (size_t)(kblk + 1) * 512);
    vfw = *reinterpret_cast<const int4v*>(vb + (size_t)(kblk + 1) * 512);

    int4v a1w, a2w;
    a1w[0] = kc[0]; a1w[1] = kc[1]; a1w[2] = 0; a1w[3] = 0;
    a2w[0] = kc[2]; a2w[1] = kc[3]; a2w[2] = 0; a2w[3] = 0;
    short8 a1, a2, vf;
    __builtin_memcpy(&a1, &a1w, 16);
    __builtin_memcpy(&a2, &a2w, 16);
    __builtin_memcpy(&vf, &vc, 16);

    const f32x4 s0 = __builtin_amdgcn_mfma_f32_16x16x32_bf16(a1, qf8, zc, 0, 0, 0);
    const f32x4 s1 = __builtin_amdgcn_mfma_f32_16x16x32_bf16(a2, qf8, zc, 0, 0, 0);

    const uint32_t wsh = adj_lds[q][kblk] >> (4 * g);   // keys 4g+i -> bits i / 16+i

    const float p0 = mexp(s0[0], wsh, 0),  p1 = mexp(s0[1], wsh, 1);
    const float p2 = mexp(s0[2], wsh, 2),  p3 = mexp(s0[3], wsh, 3);
    const float p4 = mexp(s1[0], wsh, 16), p5 = mexp(s1[1], wsh, 17);
    const float p6 = mexp(s1[2], wsh, 18), p7 = mexp(s1[3], wsh, 19);
    S += ((p0 + p1) + (p2 + p3)) + ((p4 + p5) + (p6 + p7));

    int4v paw;
    paw[0] = (int)cvt_pk_bf16(p0, p1);
    paw[1] = (int)cvt_pk_bf16(p2, p3);
    paw[2] = (int)cvt_pk_bf16(p4, p5);
    paw[3] = (int)cvt_pk_bf16(p6, p7);
    short8 pa; __builtin_memcpy(&pa, &paw, 16);

    acc = __builtin_amdgcn_mfma_f32_16x16x32_bf16(pa, vf, acc, 0, 0, 0);
  }

  // ---- S reduce over the 4 lane-groups holding the same q ----
  S += __shfl_xor(S, 16);
  S += __shfl_xor(S, 32);

  // acc[i] = out[q=4g+i][kd=l&15] (unnormalized); park in LDS
  #pragma unroll
  for (int i = 0; i < 4; ++i) heads[4 * g + i][hd * 16 + q] = acc[i];
  if (l < 16) S_lds[hd][l] = S;
  __syncthreads();
  if (t < 128) S_lds[t >> 4][t & 15] = 1.0f / S_lds[t >> 4][t & 15];
  __syncthreads();
  #pragma unroll
  for (int i = 0; i < 4; ++i) {
    const int idx = t + i * 512;
    const int rr = idx >> 7, cc = idx & 127;
    heads[rr][cc] *= S_lds[cc >> 4][rr];
  }
  __syncthreads();

  // ---- MFMA output projection + residual: wave hd = e-tile, 4 k-steps of 32 ----
  // A lane l elem e: heads[q=l&15][hk = (e&3)+4g+16*(e>>2)+32*k]  (same k-map as WoutF)
  f32x4 od = {0.f, 0.f, 0.f, 0.f};
  const uint16_t* wfp = WoutF + ((size_t)hd * 4) * 512 + (size_t)l * 8;
  #pragma unroll
  for (int k = 0; k < 4; ++k) {
    const float* hr = &heads[q][32 * k + 4 * g];
    int4v aw;
    aw[0] = (int)cvt_pk_bf16(hr[0],  hr[1]);
    aw[1] = (int)cvt_pk_bf16(hr[2],  hr[3]);
    aw[2] = (int)cvt_pk_bf16(hr[16], hr[17]);
    aw[3] = (int)cvt_pk_bf16(hr[18], hr[19]);
    short8 af; __builtin_memcpy(&af, &aw, 16);
    const short8 bf = *reinterpret_cast<const short8*>(wfp + (size_t)k * 512);
    od = __builtin_amdgcn_mfma_f32_16x16x32_bf16(af, bf, od, 0, 0, 0);
  }
  // D: row = 4g+i = q-row, col = l&15 = e within tile hd
  const size_t orow0 = (size_t)b * Nc + qblk * 16;
  const int ecol = hd * 16 + q;
  #pragma unroll
  for (int i = 0; i < 4; ++i) {
    const size_t off = (orow0 + 4 * g + i) * Ec + ecol;
    out[off] = od[i] + hin[off];
  }
}

} // namespace

extern "C" void kernel_launch(void* const* d_in, const int* in_sizes, int n_in,
                              void* d_out, int out_size, void* d_ws, size_t ws_size,
                              hipStream_t stream) {
  (void)in_sizes; (void)n_in; (void)out_size; (void)ws_size;
  const float* h   = (const float*)d_in[0];
  const int*   adj = (const int*)d_in[1];
  const float* Wq  = (const float*)d_in[2];
  const float* Wk  = (const float*)d_in[3];
  const float* Wv  = (const float*)d_in[4];
  const float* Wo  = (const float*)d_in[5];
  float* out = (float*)d_out;

  // workspace: Qf/Kf/Vf (4 MB each) + bits (2 MB) + WoutF (32 KB)
  uint16_t* Qf = (uint16_t*)d_ws;
  uint16_t* Kf = Qf + (size_t)Bc * Hc * Nc * KDc;
  uint16_t* Vf = Kf + (size_t)Bc * Hc * Nc * KDc;
  uint32_t* bits = (uint32_t*)(Vf + (size_t)Bc * Hc * Nc * KDc);
  uint16_t* WoutF = (uint16_t*)(bits + (size_t)Bc * Nc * 32);

  qkv_kernel<<<Bc * Nc / 16, 512, 0, stream>>>(h, Wq, Wk, Wv, Wo, adj,
                                               Qf, Kf, Vf, bits, WoutF);
  attn_kernel<<<Bc * (Nc / 16), 512, 0, stream>>>(Qf, Kf, Vf, bits, WoutF, h, out);
}

// Round 14
// 61.402 us; speedup vs baseline: 1.2365x; 1.2365x over previous
//
#include <hip/hip_runtime.h>
#include <hip/hip_bf16.h>
#include <math.h>
#include <stdint.h>

namespace {

constexpr int Bc = 16, Nc = 1024, Ec = 128, Hc = 8, KDc = 16, HKc = 128;
// 1/sqrt(KD) * log2(e): fold softmax scale + base-2 conversion into Q
constexpr float SCALE = 0.25f * 1.4426950408889634f;

typedef __attribute__((ext_vector_type(4))) short short4v;
typedef __attribute__((ext_vector_type(8))) short short8;
typedef __attribute__((ext_vector_type(4))) float f32x4;
typedef __attribute__((ext_vector_type(4))) int int4v;

__device__ inline uint16_t f2bf(float f) {
  __hip_bfloat16 h = __float2bfloat16(f);
  uint16_t s; __builtin_memcpy(&s, &h, 2);
  return s;
}

// RNE pair pack for output stores
__device__ inline uint32_t pk2(float a, float b) {
  return (uint32_t)f2bf(a) | ((uint32_t)f2bf(b) << 16);
}

// packed f32->bf16 (P-values / epilogue fragments)
__device__ inline uint32_t cvt_pk_bf16(float a, float b) {
  uint32_t r;
  asm("v_cvt_pk_bf16_f32 %0, %1, %2" : "=v"(r) : "v"(a), "v"(b));
  return r;
}

// masked exp2: p = exp2(s) if adjacency bit set else 0  (sbfe -> 0/-1 mask)
__device__ inline float mexp(float s, uint32_t w, int bit) {
  const uint32_t m = (uint32_t)__builtin_amdgcn_sbfe((int)w, bit, 1);
  return __uint_as_float(__float_as_uint(__builtin_amdgcn_exp2f(s)) & m);
}

// hi/lo split: x ~= hi + lo, both bf16 RNE
__device__ inline void split8(const float* x, short8& hi, short8& lo) {
  #pragma unroll
  for (int i = 0; i < 8; ++i) {
    const uint16_t h = f2bf(x[i]);
    hi[i] = (short)h;
    lo[i] = (short)f2bf(x[i] - __uint_as_float((uint32_t)h << 16));
  }
}
__device__ inline short8 round8(const float* x) {
  short8 r;
  #pragma unroll
  for (int i = 0; i < 8; ++i) r[i] = (short)f2bf(x[i]);
  return r;
}

// ---------------- Kernel 1: MFMA QKV projection (hi/lo) + WoutF pack ----------------
// r10/r11 structure exactly (measured 25-29 us twice): 512 blocks x 512 threads,
// 32 tokens/block, full 16B K/V stores. NO adjacency work (moved to attn).
__global__ __launch_bounds__(512) void qkv_kernel(
    const float* __restrict__ hin,
    const float* __restrict__ Wq, const float* __restrict__ Wk, const float* __restrict__ Wv,
    const float* __restrict__ Wout,
    uint16_t* __restrict__ Qf, uint16_t* __restrict__ Kf, uint16_t* __restrict__ Vf,
    uint16_t* __restrict__ WoutF)
{
  const int t = threadIdx.x;
  const int hd = t >> 6;            // wave = head
  const int l = t & 63;
  const int g = l >> 4, c = l & 15;

  // ---- Wout fragment pack (block 0 only; 16384 elems, 32/thread) ----
  if (blockIdx.x == 0) {
    #pragma unroll 4
    for (int it = 0; it < 32; ++it) {
      const int idx = t + it * 512;
      const int elem = idx & 7, lane = (idx >> 3) & 63;
      const int kstep = (idx >> 9) & 3, etile = idx >> 11;
      const int hk = (elem & 3) + 4 * (lane >> 4) + 16 * (elem >> 2) + 32 * kstep;
      const int e = etile * 16 + (lane & 15);
      WoutF[idx] = f2bf(Wout[hk * 128 + e]);
    }
  }

  const int tokenblk = blockIdx.x;  // 32 tokens per block
  const int b = tokenblk >> 5;
  const int kblk = tokenblk & 31;

  f32x4 Qa0 = {0,0,0,0}, Qa1 = {0,0,0,0};
  f32x4 Ka0 = {0,0,0,0}, Ka1 = {0,0,0,0};
  f32x4 Va0 = {0,0,0,0}, Va1 = {0,0,0,0};

  #pragma unroll
  for (int s = 0; s < 4; ++s) {
    const int ebase = (s * 32 + 4 * g) * 16 + c;
    const float* wqp = Wq + hd * 2048 + ebase;
    const float* wkp = Wk + hd * 2048 + ebase;
    const float* wvp = Wv + hd * 2048 + ebase;
    float wx[8];
    short8 wqh, wql, wkh, wkl, wv8;
    wx[0]=wqp[0]; wx[1]=wqp[16]; wx[2]=wqp[32]; wx[3]=wqp[48];
    wx[4]=wqp[256]; wx[5]=wqp[272]; wx[6]=wqp[288]; wx[7]=wqp[304];
    split8(wx, wqh, wql);
    wx[0]=wkp[0]; wx[1]=wkp[16]; wx[2]=wkp[32]; wx[3]=wkp[48];
    wx[4]=wkp[256]; wx[5]=wkp[272]; wx[6]=wkp[288]; wx[7]=wkp[304];
    split8(wx, wkh, wkl);
    wx[0]=wvp[0]; wx[1]=wvp[16]; wx[2]=wvp[32]; wx[3]=wvp[48];
    wx[4]=wvp[256]; wx[5]=wvp[272]; wx[6]=wvp[288]; wx[7]=wvp[304];
    wv8 = round8(wx);

    #pragma unroll
    for (int tile = 0; tile < 2; ++tile) {
      const size_t grow = (size_t)tokenblk * 32 + tile * 16 + c;
      const float4 lo4 = *reinterpret_cast<const float4*>(hin + grow * 128 + s * 32 + 4 * g);
      const float4 hi4 = *reinterpret_cast<const float4*>(hin + grow * 128 + s * 32 + 16 + 4 * g);
      float hx[8];
      hx[0]=lo4.x; hx[1]=lo4.y; hx[2]=lo4.z; hx[3]=lo4.w;
      hx[4]=hi4.x; hx[5]=hi4.y; hx[6]=hi4.z; hx[7]=hi4.w;
      short8 hh, hl; split8(hx, hh, hl);

      if (tile == 0) {
        Qa0 = __builtin_amdgcn_mfma_f32_16x16x32_bf16(wqh, hh, Qa0, 0, 0, 0);
        Qa0 = __builtin_amdgcn_mfma_f32_16x16x32_bf16(wqh, hl, Qa0, 0, 0, 0);
        Qa0 = __builtin_amdgcn_mfma_f32_16x16x32_bf16(wql, hh, Qa0, 0, 0, 0);
        Ka0 = __builtin_amdgcn_mfma_f32_16x16x32_bf16(wkh, hh, Ka0, 0, 0, 0);
        Ka0 = __builtin_amdgcn_mfma_f32_16x16x32_bf16(wkh, hl, Ka0, 0, 0, 0);
        Ka0 = __builtin_amdgcn_mfma_f32_16x16x32_bf16(wkl, hh, Ka0, 0, 0, 0);
        Va0 = __builtin_amdgcn_mfma_f32_16x16x32_bf16(hh, wv8, Va0, 0, 0, 0);
        Va0 = __builtin_amdgcn_mfma_f32_16x16x32_bf16(hl, wv8, Va0, 0, 0, 0);
      } else {
        Qa1 = __builtin_amdgcn_mfma_f32_16x16x32_bf16(wqh, hh, Qa1, 0, 0, 0);
        Qa1 = __builtin_amdgcn_mfma_f32_16x16x32_bf16(wqh, hl, Qa1, 0, 0, 0);
        Qa1 = __builtin_amdgcn_mfma_f32_16x16x32_bf16(wql, hh, Qa1, 0, 0, 0);
        Ka1 = __builtin_amdgcn_mfma_f32_16x16x32_bf16(wkh, hh, Ka1, 0, 0, 0);
        Ka1 = __builtin_amdgcn_mfma_f32_16x16x32_bf16(wkh, hl, Ka1, 0, 0, 0);
        Ka1 = __builtin_amdgcn_mfma_f32_16x16x32_bf16(wkl, hh, Ka1, 0, 0, 0);
        Va1 = __builtin_amdgcn_mfma_f32_16x16x32_bf16(hh, wv8, Va1, 0, 0, 0);
        Va1 = __builtin_amdgcn_mfma_f32_16x16x32_bf16(hl, wv8, Va1, 0, 0, 0);
      }
    }
  }

  const int qt0 = kblk * 2;
  {
    uint2 q0, q1;
    q0.x = pk2(Qa0[0] * SCALE, Qa0[1] * SCALE);
    q0.y = pk2(Qa0[2] * SCALE, Qa0[3] * SCALE);
    q1.x = pk2(Qa1[0] * SCALE, Qa1[1] * SCALE);
    q1.y = pk2(Qa1[2] * SCALE, Qa1[3] * SCALE);
    uint16_t* qp = Qf + ((((size_t)b * Hc + hd) * 64 + qt0) * 64 + l) * 4;
    *reinterpret_cast<uint2*>(qp) = q0;
    *reinterpret_cast<uint2*>(qp + 256) = q1;
  }
  {
    int4v kw;
    kw[0] = (int)pk2(Ka0[0], Ka0[1]); kw[1] = (int)pk2(Ka0[2], Ka0[3]);
    kw[2] = (int)pk2(Ka1[0], Ka1[1]); kw[3] = (int)pk2(Ka1[2], Ka1[3]);
    *reinterpret_cast<int4v*>(Kf + ((((size_t)b * Hc + hd) * 32 + kblk) * 64 + l) * 8) = kw;
    int4v vw;
    vw[0] = (int)pk2(Va0[0], Va0[1]); vw[1] = (int)pk2(Va0[2], Va0[3]);
    vw[2] = (int)pk2(Va1[0], Va1[1]); vw[3] = (int)pk2(Va1[2], Va1[3]);
    *reinterpret_cast<int4v*>(Vf + ((((size_t)b * Hc + hd) * 32 + kblk) * 64 + l) * 8) = vw;
  }
}

// ---------------- Kernel 2: 16x16-fragment MFMA masked attention + MFMA out-proj ----
// r12/r13 main loop + epilogue (validated, ~15 us). Adjacency mask now built
// INLINE from raw adj: thread = (row = t>>5, word = t&31) reads 32 ints (8 x int4,
// coalesced) and packs bits with (v&1)<<i (adj is 0/1 by construction).
__global__ __launch_bounds__(512, 4) void attn_kernel(
    const uint16_t* __restrict__ Qf, const uint16_t* __restrict__ Kf,
    const uint16_t* __restrict__ Vf, const int* __restrict__ adj,
    const uint16_t* __restrict__ WoutF,
    const float* __restrict__ hin, float* __restrict__ out)
{
  __shared__ uint32_t adj_lds[16][33];   // [q-row][word], padded
  __shared__ float heads[16][132];       // [q-row][h*16+kd], padded
  __shared__ float S_lds[8][16];         // [head][q-row]

  const int t = threadIdx.x;
  // XCD-aware swizzle: 1024 blocks, 128/XCD
  const int bid = blockIdx.x;
  const int swz = (bid & 7) * 128 + (bid >> 3);
  const int b = swz >> 6;
  const int qblk = swz & 63;
  const int hd = t >> 6, l = t & 63;
  const int g = l >> 4, q = l & 15;

  // ---- issue adjacency loads early (8 x int4 per thread, coalesced) ----
  const int arow = t >> 5, aword = t & 31;
  int4v araw[8];
  {
    const int4v* ap = reinterpret_cast<const int4v*>(
        adj + ((size_t)(b * Nc + qblk * 16 + arow)) * Nc + aword * 32);
    #pragma unroll
    for (int j = 0; j < 8; ++j) araw[j] = ap[j];
  }

  // Q fragment: 4 bf16 (kd = 4g+i), upper 4 k-slots zero
  const short4v q4 = *reinterpret_cast<const short4v*>(
      Qf + ((((size_t)b * Hc + hd) * 64 + qblk) * 64 + l) * 4);
  short8 qf8;
  #pragma unroll
  for (int i = 0; i < 4; ++i) { qf8[i] = q4[i]; qf8[4 + i] = 0; }

  // ---- pack the 32 ints into one bit-word ----
  {
    uint32_t wacc = 0;
    #pragma unroll
    for (int j = 0; j < 8; ++j) {
      #pragma unroll
      for (int i = 0; i < 4; ++i)
        wacc |= (uint32_t)(araw[j][i] & 1) << (j * 4 + i);
    }
    adj_lds[arow][aword] = wacc;
  }
  __syncthreads();

  f32x4 acc = {0.f, 0.f, 0.f, 0.f};
  const f32x4 zc = {0.f, 0.f, 0.f, 0.f};
  float S = 0.f;

  const uint16_t* kb = Kf + (((size_t)b * Hc + hd) * 32) * 512 + (size_t)l * 8;
  const uint16_t* vb = Vf + (((size_t)b * Hc + hd) * 32) * 512 + (size_t)l * 8;

  // prologue: loads for kblk = 0
  int4v kfw = *reinterpret_cast<const int4v*>(kb);
  int4v vfw = *reinterpret_cast<const int4v*>(vb);

  #pragma unroll 2
  for (int kblk = 0; kblk < 32; ++kblk) {
    const int4v kc = kfw, vc = vfw;
    // prefetch next iteration (one-past-end lands in adjacent mapped workspace)
    kfw = *reinterpret_cast<const int4v*>(kb + (size_t)(kblk + 1) * 512);
    vfw = *reinterpret_cast<const int4v*>(vb + (size_t)(kblk + 1) * 512);

    int4v a1w, a2w;
    a1w[0] = kc[0]; a1w[1] = kc[1]; a1w[2] = 0; a1w[3] = 0;
    a2w[0] = kc[2]; a2w[1] = kc[3]; a2w[2] = 0; a2w[3] = 0;
    short8 a1, a2, vf;
    __builtin_memcpy(&a1, &a1w, 16);
    __builtin_memcpy(&a2, &a2w, 16);
    __builtin_memcpy(&vf, &vc, 16);

    const f32x4 s0 = __builtin_amdgcn_mfma_f32_16x16x32_bf16(a1, qf8, zc, 0, 0, 0);
    const f32x4 s1 = __builtin_amdgcn_mfma_f32_16x16x32_bf16(a2, qf8, zc, 0, 0, 0);

    const uint32_t wsh = adj_lds[q][kblk] >> (4 * g);   // keys 4g+i -> bits i / 16+i

    const float p0 = mexp(s0[0], wsh, 0),  p1 = mexp(s0[1], wsh, 1);
    const float p2 = mexp(s0[2], wsh, 2),  p3 = mexp(s0[3], wsh, 3);
    const float p4 = mexp(s1[0], wsh, 16), p5 = mexp(s1[1], wsh, 17);
    const float p6 = mexp(s1[2], wsh, 18), p7 = mexp(s1[3], wsh, 19);
    S += ((p0 + p1) + (p2 + p3)) + ((p4 + p5) + (p6 + p7));

    int4v paw;
    paw[0] = (int)cvt_pk_bf16(p0, p1);
    paw[1] = (int)cvt_pk_bf16(p2, p3);
    paw[2] = (int)cvt_pk_bf16(p4, p5);
    paw[3] = (int)cvt_pk_bf16(p6, p7);
    short8 pa; __builtin_memcpy(&pa, &paw, 16);

    acc = __builtin_amdgcn_mfma_f32_16x16x32_bf16(pa, vf, acc, 0, 0, 0);
  }

  // ---- S reduce over the 4 lane-groups holding the same q ----
  S += __shfl_xor(S, 16);
  S += __shfl_xor(S, 32);

  // acc[i] = out[q=4g+i][kd=l&15] (unnormalized); park in LDS
  #pragma unroll
  for (int i = 0; i < 4; ++i) heads[4 * g + i][hd * 16 + q] = acc[i];
  if (l < 16) S_lds[hd][l] = S;
  __syncthreads();
  if (t < 128) S_lds[t >> 4][t & 15] = 1.0f / S_lds[t >> 4][t & 15];
  __syncthreads();
  #pragma unroll
  for (int i = 0; i < 4; ++i) {
    const int idx = t + i * 512;
    const int rr = idx >> 7, cc = idx & 127;
    heads[rr][cc] *= S_lds[cc >> 4][rr];
  }
  __syncthreads();

  // ---- MFMA output projection + residual: wave hd = e-tile, 4 k-steps of 32 ----
  // A lane l elem e: heads[q=l&15][hk = (e&3)+4g+16*(e>>2)+32*k]  (same k-map as WoutF)
  f32x4 od = {0.f, 0.f, 0.f, 0.f};
  const uint16_t* wfp = WoutF + ((size_t)hd * 4) * 512 + (size_t)l * 8;
  #pragma unroll
  for (int k = 0; k < 4; ++k) {
    const float* hr = &heads[q][32 * k + 4 * g];
    int4v aw;
    aw[0] = (int)cvt_pk_bf16(hr[0],  hr[1]);
    aw[1] = (int)cvt_pk_bf16(hr[2],  hr[3]);
    aw[2] = (int)cvt_pk_bf16(hr[16], hr[17]);
    aw[3] = (int)cvt_pk_bf16(hr[18], hr[19]);
    short8 af; __builtin_memcpy(&af, &aw, 16);
    const short8 bf = *reinterpret_cast<const short8*>(wfp + (size_t)k * 512);
    od = __builtin_amdgcn_mfma_f32_16x16x32_bf16(af, bf, od, 0, 0, 0);
  }
  // D: row = 4g+i = q-row, col = l&15 = e within tile hd
  const size_t orow0 = (size_t)b * Nc + qblk * 16;
  const int ecol = hd * 16 + q;
  #pragma unroll
  for (int i = 0; i < 4; ++i) {
    const size_t off = (orow0 + 4 * g + i) * Ec + ecol;
    out[off] = od[i] + hin[off];
  }
}

} // namespace

extern "C" void kernel_launch(void* const* d_in, const int* in_sizes, int n_in,
                              void* d_out, int out_size, void* d_ws, size_t ws_size,
                              hipStream_t stream) {
  (void)in_sizes; (void)n_in; (void)out_size; (void)ws_size;
  const float* h   = (const float*)d_in[0];
  const int*   adj = (const int*)d_in[1];
  const float* Wq  = (const float*)d_in[2];
  const float* Wk  = (const float*)d_in[3];
  const float* Wv  = (const float*)d_in[4];
  const float* Wo  = (const float*)d_in[5];
  float* out = (float*)d_out;

  // workspace: Qf/Kf/Vf (4 MB each) + WoutF (32 KB)
  uint16_t* Qf = (uint16_t*)d_ws;
  uint16_t* Kf = Qf + (size_t)Bc * Hc * Nc * KDc;
  uint16_t* Vf = Kf + (size_t)Bc * Hc * Nc * KDc;
  uint16_t* WoutF = Vf + (size_t)Bc * Hc * Nc * KDc;

  qkv_kernel<<<Bc * Nc / 32, 512, 0, stream>>>(h, Wq, Wk, Wv, Wo, Qf, Kf, Vf, WoutF);
  attn_kernel<<<Bc * (Nc / 16), 512, 0, stream>>>(Qf, Kf, Vf, adj, WoutF, h, out);
}